// Round 3
// baseline (3002.854 us; speedup 1.0000x reference)
//
#include <hip/hip_runtime.h>
#include <hip/hip_bf16.h>

typedef __hip_bfloat16 bf16;
#define DIM 128

__device__ __forceinline__ void unpack8(uint4 v, float* f) {
    const unsigned int* w = (const unsigned int*)&v;
#pragma unroll
    for (int i = 0; i < 4; i++) {
        f[2 * i]     = __uint_as_float(w[i] << 16);
        f[2 * i + 1] = __uint_as_float(w[i] & 0xffff0000u);
    }
}

// load 8 consecutive float values from a buffer that is either fp32 or bf16
__device__ __forceinline__ void load8(const void* p, int is32, size_t off, float* f) {
    if (is32) {
        const float* q = (const float*)p + off;
        float4 a = *(const float4*)q;
        float4 b = *(const float4*)(q + 4);
        f[0] = a.x; f[1] = a.y; f[2] = a.z; f[3] = a.w;
        f[4] = b.x; f[5] = b.y; f[6] = b.z; f[7] = b.w;
    } else {
        uint4 v = *(const uint4*)((const unsigned short*)p + off);
        unpack8(v, f);
    }
}

__device__ __forceinline__ int read_idx(const void* p, int is64, int e) {
    return is64 ? (int)((const long long*)p)[e] : ((const int*)p)[e];
}

// ---------------- zero workspace ----------------
__global__ void zero_f_kernel(float* __restrict__ p, int n) {
    int i = blockIdx.x * blockDim.x + threadIdx.x;
    if (i < n) p[i] = 0.0f;
}
__global__ void zero_i_kernel(int* __restrict__ p, int n) {
    int i = blockIdx.x * blockDim.x + threadIdx.x;
    if (i < n) p[i] = 0;
}

// ---------------- runtime dtype detection ----------------
__device__ int detect_is_fp32(const unsigned int* p, int nwords) {
    int n = nwords < 64 ? nwords : 64;
    int hits = 0;
    for (int i = 0; i < n; i++) {
        unsigned low = p[i] & 0xFFFFu;
        unsigned ex = (low >> 7) & 0xFFu;
        if ((ex >= 90u && ex <= 140u) || low == 0u || low == 0x8000u) hits++;
    }
    return (2 * hits < n) ? 1 : 0;   // bf16 -> hits ~ n; fp32 -> hits ~ 0.2 n
}

__global__ void detect_kernel(const unsigned int* __restrict__ src,
                              const unsigned int* __restrict__ feat,
                              const unsigned int* __restrict__ wn,
                              const unsigned int* __restrict__ wsm,
                              const unsigned int* __restrict__ bias,
                              int* __restrict__ flags) {
    if (threadIdx.x != 0 || blockIdx.x != 0) return;
    // int64 detect: int64 indices (< 2^31) have every odd 32-bit word zero
    int nz = 0;
    for (int i = 1; i < 128; i += 2) nz += (src[i] != 0u);
    flags[0] = (nz == 0) ? 1 : 0;
    flags[1] = detect_is_fp32(feat, 64);
    flags[2] = detect_is_fp32(wn, 64);
    flags[3] = detect_is_fp32(wsm, 64);
    flags[4] = detect_is_fp32(bias, 64);
}

// ---------------- degree (int atomics) ----------------
__global__ void deg_kernel(const void* __restrict__ dstv, int* __restrict__ deg,
                           const int* __restrict__ flags, int E, int N) {
    int e = blockIdx.x * blockDim.x + threadIdx.x;
    if (e >= E) return;
    int d = read_idx(dstv, flags[0], e);
    if ((unsigned)d < (unsigned)N) atomicAdd(&deg[d], 1);
}

// ---------------- scatter-add of features ----------------
// 16 threads per edge, 8 elements per thread
__global__ void scatter_kernel(const void* __restrict__ feat, const void* __restrict__ srcv,
                               const void* __restrict__ dstv, float* __restrict__ summed,
                               const int* __restrict__ flags, int E, int N, int lo, int hi) {
    long tid = (long)blockIdx.x * blockDim.x + threadIdx.x;
    int e = (int)(tid >> 4);
    int c = (int)(tid & 15) << 3;
    if (e >= E) return;
    int is64 = flags[0];
    int s = read_idx(srcv, is64, e);
    int d = read_idx(dstv, is64, e);
    if ((unsigned)s >= (unsigned)N) return;
    if (d < lo || d >= hi) return;
    float f[8];
    load8(feat, flags[1], (size_t)s * DIM + c, f);
    float* p = summed + (size_t)(d - lo) * DIM + c;
#pragma unroll
    for (int i = 0; i < 8; i++) unsafeAtomicAdd(p + i, f[i]);
}

// ---------------- fused mean + dual GEMM + bias ----------------
__global__ __launch_bounds__(256) void out_kernel(
    const void* __restrict__ feat, const float* __restrict__ summed,
    const int* __restrict__ deg, const void* __restrict__ Wn,
    const void* __restrict__ Ws, const void* __restrict__ bias,
    void* __restrict__ out, int n, int lo, int hi, const int* __restrict__ flags) {
    __shared__ float a_self[32][DIM];
    __shared__ float a_neigh[32][DIM];

    int t = threadIdx.x;
    int nb = lo + blockIdx.x * 32;
    int feat32 = flags[1], wn32 = flags[2], ws32 = flags[3], b32 = flags[4];

    // stage A tiles: thread t loads row r = t/8, 16 elems at (t%8)*16
    {
        int r = t >> 3;
        int c0 = (t & 7) << 4;
        int node = nb + r;
        if (node < hi) {
            float rd = 1.0f / fmaxf((float)deg[node], 1.0f);
#pragma unroll
            for (int ii = 0; ii < 16; ii += 8) {
                int c = c0 + ii;
                float fs[8];
                load8(feat, feat32, (size_t)node * DIM + c, fs);
                const float* sp = summed + (size_t)(node - lo) * DIM + c;
                float4 s0 = *(const float4*)sp;
                float4 s1 = *(const float4*)(sp + 4);
#pragma unroll
                for (int i = 0; i < 8; i++) a_self[r][c + i] = fs[i];
                a_neigh[r][c + 0] = s0.x * rd;
                a_neigh[r][c + 1] = s0.y * rd;
                a_neigh[r][c + 2] = s0.z * rd;
                a_neigh[r][c + 3] = s0.w * rd;
                a_neigh[r][c + 4] = s1.x * rd;
                a_neigh[r][c + 5] = s1.y * rd;
                a_neigh[r][c + 6] = s1.z * rd;
                a_neigh[r][c + 7] = s1.w * rd;
            }
        } else {
#pragma unroll
            for (int i = 0; i < 16; i++) {
                a_self[r][c0 + i] = 0.0f;
                a_neigh[r][c0 + i] = 0.0f;
            }
        }
    }
    __syncthreads();

    int j = t & 127;
    int hf = t >> 7;
    float acc[16];
    float bj = b32 ? ((const float*)bias)[j] : __bfloat162float(((const bf16*)bias)[j]);
#pragma unroll
    for (int m = 0; m < 16; m++) acc[m] = bj;

    for (int k0 = 0; k0 < DIM; k0 += 8) {
        float wsv[8], wnv[8];
        load8(Ws, ws32, (size_t)j * DIM + k0, wsv);
        load8(Wn, wn32, (size_t)j * DIM + k0, wnv);
#pragma unroll
        for (int m = 0; m < 16; m++) {
            int r = hf * 16 + m;
            float p = 0.0f;
#pragma unroll
            for (int i = 0; i < 8; i++)
                p += a_self[r][k0 + i] * wsv[i] + a_neigh[r][k0 + i] * wnv[i];
            acc[m] += p;
        }
    }

    // output dtype follows feat's dtype (reference output = promotion of inputs)
#pragma unroll
    for (int m = 0; m < 16; m++) {
        int node = nb + hf * 16 + m;
        if (node < hi) {
            size_t idx = (size_t)node * DIM + j;
            if (feat32) ((float*)out)[idx] = acc[m];
            else        ((bf16*)out)[idx] = __float2bfloat16(acc[m]);
        }
    }
}

extern "C" void kernel_launch(void* const* d_in, const int* in_sizes, int n_in,
                              void* d_out, int out_size, void* d_ws, size_t ws_size,
                              hipStream_t stream) {
    const void* feat = d_in[0];
    const void* src  = d_in[1];
    const void* dst  = d_in[2];
    const void* Wn   = d_in[3];
    const void* Ws   = d_in[4];
    const void* bias = d_in[5];

    const int N = in_sizes[0] / DIM;
    const int E = in_sizes[1];

    // workspace layout: [flags 16 ints][deg N ints (padded)][summed ...]
    int* flags = (int*)d_ws;
    int degpad = (N + 15) & ~15;
    int* deg = flags + 16;
    float* summed = (float*)(deg + degpad);

    long avail = (long)(ws_size / 4) - 16 - degpad;
    if (avail < DIM) avail = DIM;
    long npp = avail / DIM;
    if (npp > N) npp = N;
    int passes = (int)((N + npp - 1) / npp);

    zero_i_kernel<<<(16 + degpad + 255) / 256, 256, 0, stream>>>(flags, 16 + degpad);
    detect_kernel<<<1, 64, 0, stream>>>((const unsigned int*)src, (const unsigned int*)feat,
                                        (const unsigned int*)Wn, (const unsigned int*)Ws,
                                        (const unsigned int*)bias, flags);
    deg_kernel<<<(E + 255) / 256, 256, 0, stream>>>(dst, deg, flags, E, N);

    for (int p = 0; p < passes; p++) {
        int lo = (int)(p * npp);
        int hi = lo + (int)npp;
        if (hi > N) hi = N;
        int nn = hi - lo;
        zero_f_kernel<<<(nn * DIM + 255) / 256, 256, 0, stream>>>(summed, nn * DIM);
        long sthreads = (long)E * 16;
        scatter_kernel<<<(int)((sthreads + 255) / 256), 256, 0, stream>>>(
            feat, src, dst, summed, flags, E, N, lo, hi);
        out_kernel<<<(nn + 31) / 32, 256, 0, stream>>>(
            feat, summed, deg, Wn, Ws, bias, d_out, N, lo, hi, flags);
    }
}

// Round 4
// 414.672 us; speedup vs baseline: 7.2415x; 7.2415x over previous
//
#include <hip/hip_runtime.h>
#include <hip/hip_bf16.h>

typedef __hip_bfloat16 bf16;
#define DIM 128

__device__ __forceinline__ void unpack8(uint4 v, float* f) {
    const unsigned int* w = (const unsigned int*)&v;
#pragma unroll
    for (int i = 0; i < 4; i++) {
        f[2 * i]     = __uint_as_float(w[i] << 16);
        f[2 * i + 1] = __uint_as_float(w[i] & 0xffff0000u);
    }
}

// load 8 consecutive float values from a buffer that is either fp32 or bf16
__device__ __forceinline__ void load8(const void* p, int is32, size_t off, float* f) {
    if (is32) {
        const float* q = (const float*)p + off;
        float4 a = *(const float4*)q;
        float4 b = *(const float4*)(q + 4);
        f[0] = a.x; f[1] = a.y; f[2] = a.z; f[3] = a.w;
        f[4] = b.x; f[5] = b.y; f[6] = b.z; f[7] = b.w;
    } else {
        uint4 v = *(const uint4*)((const unsigned short*)p + off);
        unpack8(v, f);
    }
}

__device__ __forceinline__ int read_idx(const void* p, int is64, int e) {
    return is64 ? (int)((const long long*)p)[e] : ((const int*)p)[e];
}

// ---------------- zero ints ----------------
__global__ void zero_i_kernel(int* __restrict__ p, int n) {
    int i = blockIdx.x * blockDim.x + threadIdx.x;
    if (i < n) p[i] = 0;
}

// ---------------- runtime dtype detection ----------------
__device__ int detect_is_fp32(const unsigned int* p, int nwords) {
    int n = nwords < 64 ? nwords : 64;
    int hits = 0;
    for (int i = 0; i < n; i++) {
        unsigned low = p[i] & 0xFFFFu;
        unsigned ex = (low >> 7) & 0xFFu;
        if ((ex >= 90u && ex <= 140u) || low == 0u || low == 0x8000u) hits++;
    }
    return (2 * hits < n) ? 1 : 0;   // bf16 -> hits ~ n; fp32 -> hits ~ 0.2 n
}

__global__ void detect_kernel(const unsigned int* __restrict__ src,
                              const unsigned int* __restrict__ feat,
                              const unsigned int* __restrict__ wn,
                              const unsigned int* __restrict__ wsm,
                              const unsigned int* __restrict__ bias,
                              int* __restrict__ flags) {
    if (threadIdx.x != 0 || blockIdx.x != 0) return;
    int nz = 0;
    for (int i = 1; i < 128; i += 2) nz += (src[i] != 0u);
    flags[0] = (nz == 0) ? 1 : 0;     // int64 indices?
    flags[1] = detect_is_fp32(feat, 64);
    flags[2] = detect_is_fp32(wn, 64);
    flags[3] = detect_is_fp32(wsm, 64);
    flags[4] = detect_is_fp32(bias, 64);
}

// ---------------- degree (int atomics) ----------------
__global__ void deg_kernel(const void* __restrict__ dstv, int* __restrict__ deg,
                           const int* __restrict__ flags, int E, int N) {
    int e = blockIdx.x * blockDim.x + threadIdx.x;
    if (e >= E) return;
    int d = read_idx(dstv, flags[0], e);
    if ((unsigned)d < (unsigned)N) atomicAdd(&deg[d], 1);
}

// ---------------- exclusive scan over deg -> off[0..N] ----------------
// single block, 1024 threads, each handles a contiguous chunk
__global__ __launch_bounds__(1024) void scan_kernel(const int* __restrict__ deg,
                                                    int* __restrict__ off, int N) {
    __shared__ int part[1024];
    int t = threadIdx.x;
    int chunk = (N + 1023) / 1024;
    int base = t * chunk;
    int s = 0;
    for (int i = 0; i < chunk; i++) {
        int idx = base + i;
        if (idx < N) s += deg[idx];
    }
    part[t] = s;
    __syncthreads();
    // Hillis-Steele inclusive scan
    for (int d = 1; d < 1024; d <<= 1) {
        int v = (t >= d) ? part[t - d] : 0;
        __syncthreads();
        part[t] += v;
        __syncthreads();
    }
    int run = (t == 0) ? 0 : part[t - 1];
    for (int i = 0; i < chunk; i++) {
        int idx = base + i;
        if (idx <= N) {
            off[idx] = run;
            if (idx < N) run += deg[idx];
        }
    }
}

// ---------------- CSR fill: bucket src ids by dst ----------------
__global__ void fill_kernel(const void* __restrict__ srcv, const void* __restrict__ dstv,
                            const int* __restrict__ flags, const int* __restrict__ off,
                            int* __restrict__ cursor, int* __restrict__ edge_csr,
                            int E, int N) {
    int e = blockIdx.x * blockDim.x + threadIdx.x;
    if (e >= E) return;
    int is64 = flags[0];
    int s = read_idx(srcv, is64, e);
    int d = read_idx(dstv, is64, e);
    if ((unsigned)s >= (unsigned)N || (unsigned)d >= (unsigned)N) return;
    int pos = atomicAdd(&cursor[d], 1);
    edge_csr[off[d] + pos] = s;
}

// ---------------- fused gather + mean + dual GEMM + bias ----------------
// block = 256 threads, 32 nodes/block; 8 threads per node, 16 elems/thread
__global__ __launch_bounds__(256) void out_kernel(
    const void* __restrict__ feat, const int* __restrict__ off,
    const int* __restrict__ edge_csr, const void* __restrict__ Wn,
    const void* __restrict__ Ws, const void* __restrict__ bias,
    void* __restrict__ out, int N, const int* __restrict__ flags) {
    __shared__ float a_self[32][DIM];
    __shared__ float a_neigh[32][DIM];

    int t = threadIdx.x;
    int nb = blockIdx.x * 32;
    int feat32 = flags[1], wn32 = flags[2], ws32 = flags[3], b32 = flags[4];

    // ---- gather phase ----
    {
        int r = t >> 3;
        int c0 = (t & 7) << 4;
        int node = nb + r;
        float accn[16];
#pragma unroll
        for (int i = 0; i < 16; i++) accn[i] = 0.0f;

        if (node < N) {
            float fs[16];
            load8(feat, feat32, (size_t)node * DIM + c0, fs);
            load8(feat, feat32, (size_t)node * DIM + c0 + 8, fs + 8);
#pragma unroll
            for (int i = 0; i < 16; i++) a_self[r][c0 + i] = fs[i];

            int e0 = off[node];
            int e1 = off[node + 1];
            for (int e = e0; e < e1; e++) {
                int s = edge_csr[e];
                float f[16];
                load8(feat, feat32, (size_t)s * DIM + c0, f);
                load8(feat, feat32, (size_t)s * DIM + c0 + 8, f + 8);
#pragma unroll
                for (int i = 0; i < 16; i++) accn[i] += f[i];
            }
            float rd = 1.0f / fmaxf((float)(e1 - e0), 1.0f);
#pragma unroll
            for (int i = 0; i < 16; i++) a_neigh[r][c0 + i] = accn[i] * rd;
        } else {
#pragma unroll
            for (int i = 0; i < 16; i++) {
                a_self[r][c0 + i] = 0.0f;
                a_neigh[r][c0 + i] = 0.0f;
            }
        }
    }
    __syncthreads();

    // ---- GEMM phase: thread t -> col j = t&127, rows (t>>7)*16..+15 ----
    int j = t & 127;
    int hf = t >> 7;
    float acc[16];
    float bj = b32 ? ((const float*)bias)[j] : __bfloat162float(((const bf16*)bias)[j]);
#pragma unroll
    for (int m = 0; m < 16; m++) acc[m] = bj;

    for (int k0 = 0; k0 < DIM; k0 += 8) {
        float wsv[8], wnv[8];
        load8(Ws, ws32, (size_t)j * DIM + k0, wsv);
        load8(Wn, wn32, (size_t)j * DIM + k0, wnv);
#pragma unroll
        for (int m = 0; m < 16; m++) {
            int r = hf * 16 + m;
            float p = 0.0f;
#pragma unroll
            for (int i = 0; i < 8; i++)
                p += a_self[r][k0 + i] * wsv[i] + a_neigh[r][k0 + i] * wnv[i];
            acc[m] += p;
        }
    }

#pragma unroll
    for (int m = 0; m < 16; m++) {
        int node = nb + hf * 16 + m;
        if (node < N) {
            size_t idx = (size_t)node * DIM + j;
            if (feat32) ((float*)out)[idx] = acc[m];
            else        ((bf16*)out)[idx] = __float2bfloat16(acc[m]);
        }
    }
}

extern "C" void kernel_launch(void* const* d_in, const int* in_sizes, int n_in,
                              void* d_out, int out_size, void* d_ws, size_t ws_size,
                              hipStream_t stream) {
    const void* feat = d_in[0];
    const void* src  = d_in[1];
    const void* dst  = d_in[2];
    const void* Wn   = d_in[3];
    const void* Ws   = d_in[4];
    const void* bias = d_in[5];

    const int N = in_sizes[0] / DIM;
    const int E = in_sizes[1];

    // workspace layout (ints): flags(16) | deg(N) | cursor(N) | off(N+1) | edge_csr(E)
    int* flags    = (int*)d_ws;
    int* deg      = flags + 16;
    int* cursor   = deg + N;
    int* off      = cursor + N;
    int* edge_csr = off + (N + 1);

    // zero flags + deg + cursor in one shot (contiguous)
    int nz = 16 + 2 * N;
    zero_i_kernel<<<(nz + 255) / 256, 256, 0, stream>>>(flags, nz);
    detect_kernel<<<1, 64, 0, stream>>>((const unsigned int*)src, (const unsigned int*)feat,
                                        (const unsigned int*)Wn, (const unsigned int*)Ws,
                                        (const unsigned int*)bias, flags);
    deg_kernel<<<(E + 255) / 256, 256, 0, stream>>>(dst, deg, flags, E, N);
    scan_kernel<<<1, 1024, 0, stream>>>(deg, off, N);
    fill_kernel<<<(E + 255) / 256, 256, 0, stream>>>(src, dst, flags, off, cursor, edge_csr, E, N);
    out_kernel<<<(N + 31) / 32, 256, 0, stream>>>(feat, off, edge_csr, Wn, Ws, bias, d_out, N, flags);
}

// Round 5
// 359.110 us; speedup vs baseline: 8.3619x; 1.1547x over previous
//
#include <hip/hip_runtime.h>
#include <hip/hip_bf16.h>

typedef __hip_bfloat16 bf16;
#define DIM 128

__device__ __forceinline__ float bfbits(unsigned short u) {
    return __uint_as_float(((unsigned)u) << 16);
}
__device__ __forceinline__ unsigned short f2bf(float f) {
    bf16 h = __float2bfloat16(f);
    return *(unsigned short*)&h;
}
__device__ __forceinline__ void unpack8(uint4 v, float* f) {
    const unsigned int* w = (const unsigned int*)&v;
#pragma unroll
    for (int i = 0; i < 4; i++) {
        f[2 * i]     = __uint_as_float(w[i] << 16);
        f[2 * i + 1] = __uint_as_float(w[i] & 0xffff0000u);
    }
}
__device__ __forceinline__ void load8(const void* p, int is32, size_t off, float* f) {
    if (is32) {
        const float* q = (const float*)p + off;
        float4 a = *(const float4*)q;
        float4 b = *(const float4*)(q + 4);
        f[0] = a.x; f[1] = a.y; f[2] = a.z; f[3] = a.w;
        f[4] = b.x; f[5] = b.y; f[6] = b.z; f[7] = b.w;
    } else {
        uint4 v = *(const uint4*)((const unsigned short*)p + off);
        unpack8(v, f);
    }
}
__device__ __forceinline__ int read_idx(const void* p, int is64, int e) {
    return is64 ? (int)((const long long*)p)[e] : ((const int*)p)[e];
}

// ---------------- zero ints ----------------
__global__ void zero_i_kernel(int* __restrict__ p, int n) {
    int i = blockIdx.x * blockDim.x + threadIdx.x;
    if (i < n) p[i] = 0;
}

// ---------------- runtime dtype detection (one wave) ----------------
__device__ __forceinline__ int is_fp32_wave(const unsigned int* p, int lane) {
    unsigned w = p[lane];
    unsigned low = w & 0xFFFFu;
    unsigned ex = (low >> 7) & 0xFFu;
    bool hit = (ex >= 90u && ex <= 140u) || low == 0u || low == 0x8000u;
    unsigned long long m = __ballot(hit);
    return (2 * __popcll(m) < 64) ? 1 : 0;
}
__global__ void detect_kernel(const unsigned int* __restrict__ src,
                              const unsigned int* __restrict__ feat,
                              const unsigned int* __restrict__ wn,
                              const unsigned int* __restrict__ wsm,
                              const unsigned int* __restrict__ bias,
                              int* __restrict__ flags) {
    int lane = threadIdx.x & 63;
    // int64 indices (< 2^31): every odd 32-bit word is zero
    unsigned long long m = __ballot(src[1 + 2 * lane] != 0u);
    int f1 = is_fp32_wave(feat, lane);
    int f2 = is_fp32_wave(wn, lane);
    int f3 = is_fp32_wave(wsm, lane);
    int f4 = is_fp32_wave(bias, lane);
    if (lane == 0) {
        flags[0] = (m == 0ull) ? 1 : 0;
        flags[1] = f1; flags[2] = f2; flags[3] = f3; flags[4] = f4;
    }
}

// ---------------- degree (int atomics) ----------------
__global__ void deg_kernel(const void* __restrict__ dstv, int* __restrict__ deg,
                           const int* __restrict__ flags, int E, int N) {
    int e = blockIdx.x * blockDim.x + threadIdx.x;
    if (e >= E) return;
    int d = read_idx(dstv, flags[0], e);
    if ((unsigned)d < (unsigned)N) atomicAdd(&deg[d], 1);
}

// ---------------- 3-phase parallel exclusive scan ----------------
#define SCHUNK 1024
__global__ __launch_bounds__(256) void scan1_kernel(const int* __restrict__ deg,
                                                    int* __restrict__ blocksum, int N) {
    __shared__ int red[256];
    int b = blockIdx.x, t = threadIdx.x;
    int base = b * SCHUNK + t * 4;
    int s = 0;
    if (base + 3 < N) {
        int4 q = *(const int4*)(deg + base);
        s = q.x + q.y + q.z + q.w;
    } else {
#pragma unroll
        for (int i = 0; i < 4; i++) if (base + i < N) s += deg[base + i];
    }
    red[t] = s;
    __syncthreads();
    for (int d = 128; d > 0; d >>= 1) {
        if (t < d) red[t] += red[t + d];
        __syncthreads();
    }
    if (t == 0) blocksum[b] = red[0];
}

__global__ __launch_bounds__(1024) void scan2_kernel(const int* __restrict__ blocksum,
                                                     int* __restrict__ blockoff, int nb,
                                                     int* __restrict__ offN) {
    __shared__ int sh[1024];
    int t = threadIdx.x;
    int v = (t < nb) ? blocksum[t] : 0;
    sh[t] = v;
    __syncthreads();
    for (int d = 1; d < 1024; d <<= 1) {
        int u = (t >= d) ? sh[t - d] : 0;
        __syncthreads();
        sh[t] += u;
        __syncthreads();
    }
    if (t < nb) blockoff[t] = sh[t] - v;  // exclusive
    if (t == 0) *offN = sh[1023];         // total (padded zeros beyond nb)
}

__global__ __launch_bounds__(256) void scan3_kernel(const int* __restrict__ deg,
                                                    const int* __restrict__ blockoff,
                                                    int* __restrict__ off, int N) {
    __shared__ int red[256];
    int b = blockIdx.x, t = threadIdx.x;
    int base = b * SCHUNK + t * 4;
    int d0 = 0, d1 = 0, d2 = 0, d3 = 0;
    if (base + 3 < N) {
        int4 q = *(const int4*)(deg + base);
        d0 = q.x; d1 = q.y; d2 = q.z; d3 = q.w;
    } else {
        if (base + 0 < N) d0 = deg[base + 0];
        if (base + 1 < N) d1 = deg[base + 1];
        if (base + 2 < N) d2 = deg[base + 2];
        if (base + 3 < N) d3 = deg[base + 3];
    }
    int tot = d0 + d1 + d2 + d3;
    red[t] = tot;
    __syncthreads();
    for (int d = 1; d < 256; d <<= 1) {
        int u = (t >= d) ? red[t - d] : 0;
        __syncthreads();
        red[t] += u;
        __syncthreads();
    }
    int texcl = red[t] - tot + blockoff[b];
    if (base + 0 < N) off[base + 0] = texcl;
    if (base + 1 < N) off[base + 1] = texcl + d0;
    if (base + 2 < N) off[base + 2] = texcl + d0 + d1;
    if (base + 3 < N) off[base + 3] = texcl + d0 + d1 + d2;
}

// ---------------- CSR fill ----------------
__global__ void fill_kernel(const void* __restrict__ srcv, const void* __restrict__ dstv,
                            const int* __restrict__ flags, const int* __restrict__ off,
                            int* __restrict__ cursor, int* __restrict__ edge_csr,
                            int E, int N) {
    int e = blockIdx.x * blockDim.x + threadIdx.x;
    if (e >= E) return;
    int is64 = flags[0];
    int s = read_idx(srcv, is64, e);
    int d = read_idx(dstv, is64, e);
    if ((unsigned)s >= (unsigned)N || (unsigned)d >= (unsigned)N) return;
    int pos = atomicAdd(&cursor[d], 1);
    edge_csr[off[d] + pos] = s;
}

// ---------------- fused gather + mean + dual GEMM + bias ----------------
// block = 256 (4 waves), 32 nodes/block.
// Gather: wave w handles nodes nb+w*8..+7; lane covers dims 2*lane, 2*lane+1 (coalesced 512B/row).
// GEMM: thread -> cols j0,j0+1 = (t&63)*2, rows rg*8..+7 (rg = t>>6).
__global__ __launch_bounds__(256) void out_kernel(
    const void* __restrict__ feat, const int* __restrict__ off,
    const int* __restrict__ edge_csr, const void* __restrict__ Wn,
    const void* __restrict__ Ws, const void* __restrict__ bias,
    void* __restrict__ out, int N, const int* __restrict__ flags) {
    __shared__ float a_self[32][DIM];
    __shared__ float a_neigh[32][DIM];

    int t = threadIdx.x;
    int nb = blockIdx.x * 32;
    int feat32 = flags[1], wn32 = flags[2], ws32 = flags[3], b32 = flags[4];
    int wv = t >> 6, lane = t & 63;

    const float* featf = (const float*)feat;
    const unsigned short* feath = (const unsigned short*)feat;

    // ---- gather phase ----
    for (int i = 0; i < 8; i++) {
        int r = wv * 8 + i;
        int node = nb + r;
        float s0 = 0.f, s1 = 0.f, n0 = 0.f, n1 = 0.f;
        if (node < N) {
            if (feat32) {
                float2 v = *(const float2*)(featf + (size_t)node * DIM + lane * 2);
                s0 = v.x; s1 = v.y;
            } else {
                unsigned u = *(const unsigned*)(feath + (size_t)node * DIM + lane * 2);
                s0 = bfbits((unsigned short)u); s1 = bfbits((unsigned short)(u >> 16));
            }
            int e0 = off[node], e1 = off[node + 1];
            int e = e0;
            if (feat32) {
                for (; e + 4 <= e1; e += 4) {
                    int i0 = edge_csr[e + 0], i1 = edge_csr[e + 1];
                    int i2 = edge_csr[e + 2], i3 = edge_csr[e + 3];
                    float2 v0 = *(const float2*)(featf + (size_t)i0 * DIM + lane * 2);
                    float2 v1 = *(const float2*)(featf + (size_t)i1 * DIM + lane * 2);
                    float2 v2 = *(const float2*)(featf + (size_t)i2 * DIM + lane * 2);
                    float2 v3 = *(const float2*)(featf + (size_t)i3 * DIM + lane * 2);
                    n0 += (v0.x + v1.x) + (v2.x + v3.x);
                    n1 += (v0.y + v1.y) + (v2.y + v3.y);
                }
                for (; e < e1; e++) {
                    int s = edge_csr[e];
                    float2 v = *(const float2*)(featf + (size_t)s * DIM + lane * 2);
                    n0 += v.x; n1 += v.y;
                }
            } else {
                for (; e < e1; e++) {
                    int s = edge_csr[e];
                    unsigned u = *(const unsigned*)(feath + (size_t)s * DIM + lane * 2);
                    n0 += bfbits((unsigned short)u); n1 += bfbits((unsigned short)(u >> 16));
                }
            }
            float rd = 1.0f / fmaxf((float)(e1 - e0), 1.0f);
            n0 *= rd; n1 *= rd;
        }
        *(float2*)&a_self[r][lane * 2]  = make_float2(s0, s1);
        *(float2*)&a_neigh[r][lane * 2] = make_float2(n0, n1);
    }
    __syncthreads();

    // ---- GEMM phase ----
    int j0 = (t & 63) * 2;
    int rg = t >> 6;
    float acc0[8], acc1[8];
    float b0, b1;
    if (b32) {
        b0 = ((const float*)bias)[j0];
        b1 = ((const float*)bias)[j0 + 1];
    } else {
        b0 = bfbits(((const unsigned short*)bias)[j0]);
        b1 = bfbits(((const unsigned short*)bias)[j0 + 1]);
    }
#pragma unroll
    for (int m = 0; m < 8; m++) { acc0[m] = b0; acc1[m] = b1; }

    for (int k0 = 0; k0 < DIM; k0 += 8) {
        float ws0[8], ws1[8], wn0[8], wn1[8];
        load8(Ws, ws32, (size_t)j0 * DIM + k0, ws0);
        load8(Ws, ws32, (size_t)(j0 + 1) * DIM + k0, ws1);
        load8(Wn, wn32, (size_t)j0 * DIM + k0, wn0);
        load8(Wn, wn32, (size_t)(j0 + 1) * DIM + k0, wn1);
#pragma unroll
        for (int m = 0; m < 8; m++) {
            int r = rg * 8 + m;
            const float* as = &a_self[r][k0];
            const float* an = &a_neigh[r][k0];
            float p0 = 0.f, p1 = 0.f;
#pragma unroll
            for (int i = 0; i < 8; i++) {
                p0 += as[i] * ws0[i] + an[i] * wn0[i];
                p1 += as[i] * ws1[i] + an[i] * wn1[i];
            }
            acc0[m] += p0; acc1[m] += p1;
        }
    }

#pragma unroll
    for (int m = 0; m < 8; m++) {
        int node = nb + rg * 8 + m;
        if (node < N) {
            size_t idx = (size_t)node * DIM + j0;
            if (feat32) {
                *(float2*)((float*)out + idx) = make_float2(acc0[m], acc1[m]);
            } else {
                unsigned u = ((unsigned)f2bf(acc1[m]) << 16) | (unsigned)f2bf(acc0[m]);
                *(unsigned*)((unsigned short*)out + idx) = u;
            }
        }
    }
}

extern "C" void kernel_launch(void* const* d_in, const int* in_sizes, int n_in,
                              void* d_out, int out_size, void* d_ws, size_t ws_size,
                              hipStream_t stream) {
    const void* feat = d_in[0];
    const void* src  = d_in[1];
    const void* dst  = d_in[2];
    const void* Wn   = d_in[3];
    const void* Ws   = d_in[4];
    const void* bias = d_in[5];

    const int N = in_sizes[0] / DIM;
    const int E = in_sizes[1];

    // ws ints: flags(16) | deg(N) | cursor(N) | off(N+1) | blocksum(1024) | blockoff(1024) | edge_csr(E)
    int* flags    = (int*)d_ws;
    int* deg      = flags + 16;
    int* cursor   = deg + N;
    int* off      = cursor + N;
    int* blocksum = off + (N + 1);
    int* blockoff = blocksum + 1024;
    int* edge_csr = blockoff + 1024;

    int nb_scan = (N + SCHUNK - 1) / SCHUNK;

    int nz = 16 + 2 * N;
    zero_i_kernel<<<(nz + 255) / 256, 256, 0, stream>>>(flags, nz);
    detect_kernel<<<1, 64, 0, stream>>>((const unsigned int*)src, (const unsigned int*)feat,
                                        (const unsigned int*)Wn, (const unsigned int*)Ws,
                                        (const unsigned int*)bias, flags);
    deg_kernel<<<(E + 255) / 256, 256, 0, stream>>>(dst, deg, flags, E, N);
    scan1_kernel<<<nb_scan, 256, 0, stream>>>(deg, blocksum, N);
    scan2_kernel<<<1, 1024, 0, stream>>>(blocksum, blockoff, nb_scan, off + N);
    scan3_kernel<<<nb_scan, 256, 0, stream>>>(deg, blockoff, off, N);
    fill_kernel<<<(E + 255) / 256, 256, 0, stream>>>(src, dst, flags, off, cursor, edge_csr, E, N);
    out_kernel<<<(N + 31) / 32, 256, 0, stream>>>(feat, off, edge_csr, Wn, Ws, bias, d_out, N, flags);
}